// Round 8
// baseline (200.163 us; speedup 1.0000x reference)
//
#include <hip/hip_runtime.h>
#include <hip/hip_fp16.h>

// TrigHashGrid: B=1048576, IN_DIM=3, M=3, N=16, C=2, W=1000, A=-0.75
// R12: MEASUREMENT ROUND on the R11 structure. R11 matched prediction
// (store restructure: 75 -> ~61us dispatch) but is again invisible to
// rocprof (<80us fills). Remaining gap vs overlapped pipe floor (~24us) is
// either (a) ~37us iteration-independent cost [old marginal model], or
// (b) ~3.8us/iter unhidden latency [no-fixed model] -- opposite fixes.
// This kernel = R11 + full 16-iter REPLAY with asm-opaque base (compiler
// cannot prove addresses equal -> recomputes and re-stores identical
// values; output bitwise identical; WRITE_SIZE doubles to ~256MB as the
// execution check). marginal = (T_32 - 61)/16 with full PMC:
//   dispatch 77-87  -> fixed ~37us real; iterations ~write-bound
//   dispatch 115-125-> no fixed; per-iter latency story; deepen ILP
//   VALUBusy >= 60% -> issue-bound; instruction diet
//   conflicts >> 10.5M -> level-pair layout doubled conflict rate

constexpr float A_C = -0.75f;

#define BLK 1024
#define WPAD 1004            // 2 + 1000 + 2 positions, one __half2 each

typedef float f32x4 __attribute__((ext_vector_type(4)));

__device__ __forceinline__ float hw_sin(float a) {
    // sin(a) = v_sin_f32(fract(a / 2pi)); v_fract wraps negatives correctly.
    float rev = a * 0.15915494309189535f;
    rev = __builtin_amdgcn_fractf(rev);
    return __builtin_amdgcn_sinf(rev);
}

struct Consts {
    float Ga[2][3], Gb[2][3], Gc[2][3], Hh[2][3];
};

__device__ __forceinline__ void do_iter(
    int b, const Consts& cc,
    const __half2* lrow0, const __half2* lrow1,
    const float* __restrict__ x, f32x4* __restrict__ out4, int np)
{
    float x0 = x[b * 3 + 0];
    float x1 = x[b * 3 + 1];
    float x2 = x[b * 3 + 2];

    float2 o[2];
#pragma unroll
    for (int s = 0; s < 2; ++s) {
        float p = 1.0f;
#pragma unroll
        for (int m = 0; m < 3; ++m) {
            float a = fmaf(x0, cc.Ga[s][m],
                      fmaf(x1, cc.Gb[s][m],
                      fmaf(x2, cc.Gc[s][m], cc.Hh[s][m])));
            p *= hw_sin(a);
        }
        float ix = fmaf(p, 500.0f, 499.5f);        // [-0.5, 999.5]
        float xf = floorf(ix);
        float t  = ix - xf;
        int base = (int)xf;                        // [-1, 999]
        base = min(max(base, -1), 999);            // cheap insurance

        float u   = 1.0f - t;
        float tu  = t * u;
        float atu = A_C * tu;
        float w0  = atu * u;
        float w3  = atu * t;
        float w1  = fmaf(fmaf(A_C + 2.0f, t, -(A_C + 3.0f)), t * t, 1.0f);
        float w2  = 1.0f - w0 - w1 - w3;

        const __half2* tap = (s ? lrow1 : lrow0) + (base + 1);
        __half2 acc = __hmul2(tap[0], __float2half2_rn(w0));
        acc = __hfma2(tap[1], __float2half2_rn(w1), acc);
        acc = __hfma2(tap[2], __float2half2_rn(w2), acc);
        acc = __hfma2(tap[3], __float2half2_rn(w3), acc);
        o[s] = __half22float2(acc);
    }

    f32x4 v = { o[0].x, o[0].y, o[1].x, o[1].y };
    __builtin_nontemporal_store(v, &out4[b * 8 + np]);
}

__global__ __launch_bounds__(BLK, 8)
void trig_hashgrid(const float* __restrict__ x, const float* __restrict__ grids,
                   const float* __restrict__ G, const float* __restrict__ H,
                   float* __restrict__ out)
{
    __shared__ __half2 lds[16 * WPAD];        // 64256 B -> 2 blocks/CU
    const int tid = threadIdx.x;
    const int blk = blockIdx.x;               // 0..511

    if (tid < 64) {
        int nl = tid >> 2, j = tid & 3;
        int off = (j < 2) ? j : (WPAD - 4 + j);
        lds[nl * WPAD + off] = __floats2half2_rn(0.0f, 0.0f);
    }
    {
        int row = tid >> 6;                   // 0..15
        int j   = tid & 63;
        const float* gsrc = grids + row * 2000;
        __half2* ldst = lds + row * WPAD;
        for (int w = j; w < 1000; w += 64)
            ldst[w + 2] = __floats2half2_rn(gsrc[w], gsrc[1000 + w]);
    }

    const int np = tid & 7;                   // level pair: n = 2np, 2np+1
    const int g  = tid >> 3;                  // 0..127
    const int n0 = 2 * np, n1 = n0 + 1;

    Consts cc;
#pragma unroll
    for (int m = 0; m < 3; ++m) {
        cc.Ga[0][m] = G[0*48 + m*16 + n0]; cc.Ga[1][m] = G[0*48 + m*16 + n1];
        cc.Gb[0][m] = G[1*48 + m*16 + n0]; cc.Gb[1][m] = G[1*48 + m*16 + n1];
        cc.Gc[0][m] = G[2*48 + m*16 + n0]; cc.Gc[1][m] = G[2*48 + m*16 + n1];
        cc.Hh[0][m] = H[m*16 + n0];        cc.Hh[1][m] = H[m*16 + n1];
    }
    __syncthreads();

    f32x4* __restrict__ out4 = (f32x4*)out;
    const __half2* lrow0 = &lds[n0 * WPAD];
    const __half2* lrow1 = &lds[n1 * WPAD];

    // ---- REAL pass: identical to R11 ----
#pragma unroll 2
    for (int i = 0; i < 16; ++i)
        do_iter(blk * 128 + g + i * 65536, cc, lrow0, lrow1, x, out4, np);

    // ---- REPLAY pass: same b sequence through an opaque base. Compiler
    // cannot prove addresses equal -> full recompute + re-store of
    // bitwise-identical values (idempotent; output unchanged). Purely to
    // (1) measure the marginal per-iteration cost of THIS structure and
    // (2) lift dispatch above the 80-84us fills for PMC visibility.
    int g2 = g;
    asm volatile("" : "+v"(g2));
#pragma unroll 2
    for (int i = 0; i < 16; ++i)
        do_iter(blk * 128 + g2 + i * 65536, cc, lrow0, lrow1, x, out4, np);
}

extern "C" void kernel_launch(void* const* d_in, const int* in_sizes, int n_in,
                              void* d_out, int out_size, void* d_ws, size_t ws_size,
                              hipStream_t stream) {
    const float* x     = (const float*)d_in[0];
    const float* grids = (const float*)d_in[1];
    const float* G     = (const float*)d_in[2];
    const float* H     = (const float*)d_in[3];
    float* out = (float*)d_out;
    trig_hashgrid<<<512, BLK, 0, stream>>>(x, grids, G, H, out);
}

// Round 9
// 173.216 us; speedup vs baseline: 1.1556x; 1.1556x over previous
//
#include <hip/hip_runtime.h>
#include <hip/hip_fp16.h>

// TrigHashGrid: B=1048576, IN_DIM=3, M=3, N=16, C=2, W=1000, A=-0.75
// R13: cycle diet. R12 probe: T(32it)=82.5us, VALUBusy 56.5%, conflicts
// 2x16-iter level (pair layout fine), WRITE exact. VALU-busy time (46.6us)
// vs instruction count (~90/iter) implies sustained clock ~1.2-1.4 GHz,
// not 2.4 -- all cycle costs are worth ~2x the spec-clock model, and
// VALU/LDS/write are all near-binding with imperfect overlap. So: shave
// cycles, bitwise-safely:
//  1. G,H prescaled by 1/2pi into registers -> rev = fma chain directly
//     (-6 v_mul/iter, sin dep chain -1 op).
//  2. med3_f32 clamp on xf before int cvt (insurance only; t uses raw xf).
//  3. Pointer strength reduction: xp/op marched by constant strides
//     (kills per-iter mad_u64 address rebuilds).
//  4. Unroll 4 (VGPR 24 -> headroom); taps stay adjacent so the compiler
//     can fuse pairs into ds_read2_b32.
// Structure (16 levels/block, fp16 c-packed LDS, full-line nontemporal
// float4 stores) unchanged from R11.

constexpr float A_C = -0.75f;

#define BLK 1024
#define WPAD 1004            // 2 + 1000 + 2 positions, one __half2 each

typedef float f32x4 __attribute__((ext_vector_type(4)));

__global__ __launch_bounds__(BLK, 8)
void trig_hashgrid(const float* __restrict__ x, const float* __restrict__ grids,
                   const float* __restrict__ G, const float* __restrict__ H,
                   float* __restrict__ out)
{
    __shared__ __half2 lds[16 * WPAD];        // 64256 B -> 2 blocks/CU
    const int tid = threadIdx.x;
    const int blk = blockIdx.x;               // 0..511

    // Zero the 4 pad positions per level row (padded w {0,1,1002,1003}).
    if (tid < 64) {
        int nl = tid >> 2, j = tid & 3;
        int off = (j < 2) ? j : (WPAD - 4 + j);
        lds[nl * WPAD + off] = __floats2half2_rn(0.0f, 0.0f);
    }
    // Stage all 16 levels as packed half2(c0,c1); 64 lanes/row, coalesced.
    {
        int row = tid >> 6;                   // 0..15
        int j   = tid & 63;
        const float* gsrc = grids + row * 2000;
        __half2* ldst = lds + row * WPAD;
        for (int w = j; w < 1000; w += 64)
            ldst[w + 2] = __floats2half2_rn(gsrc[w], gsrc[1000 + w]);
    }

    const int np = tid & 7;                   // level pair: n = 2np, 2np+1
    const int g  = tid >> 3;                  // 0..127
    const int n0 = 2 * np, n1 = n0 + 1;

    // Per-pair frequencies/phases, PRESCALED by 1/2pi (v_sin_f32 takes
    // revolutions): rev = x.G' + H' directly, no per-iter mul.
    constexpr float C2PI = 0.15915494309189535f;
    float Ga[2][3], Gb[2][3], Gc[2][3], Hh[2][3];
#pragma unroll
    for (int m = 0; m < 3; ++m) {
        Ga[0][m] = G[0*48 + m*16 + n0] * C2PI; Ga[1][m] = G[0*48 + m*16 + n1] * C2PI;
        Gb[0][m] = G[1*48 + m*16 + n0] * C2PI; Gb[1][m] = G[1*48 + m*16 + n1] * C2PI;
        Gc[0][m] = G[2*48 + m*16 + n0] * C2PI; Gc[1][m] = G[2*48 + m*16 + n1] * C2PI;
        Hh[0][m] = H[m*16 + n0] * C2PI;        Hh[1][m] = H[m*16 + n1] * C2PI;
    }
    __syncthreads();

    const __half2* lrow0 = &lds[n0 * WPAD];
    const __half2* lrow1 = &lds[n1 * WPAD];

    // Strength-reduced pointers: b = blk*128 + g + i*65536.
    const float* xp = x + (blk * 128 + g) * 3;          // += 65536*3 per iter
    f32x4*       op = (f32x4*)out + (blk * 128 + g) * 8 + np;  // += 65536*8

    // 16 iterations, b stride 65536; two independent chains per thread.
#pragma unroll 4
    for (int i = 0; i < 16; ++i) {
        float x0 = xp[0];
        float x1 = xp[1];
        float x2 = xp[2];

        float2 o[2];
#pragma unroll
        for (int s = 0; s < 2; ++s) {
            float p = 1.0f;
#pragma unroll
            for (int m = 0; m < 3; ++m) {
                float rev = fmaf(x0, Ga[s][m],
                            fmaf(x1, Gb[s][m],
                            fmaf(x2, Gc[s][m], Hh[s][m])));
                rev = __builtin_amdgcn_fractf(rev);
                p *= __builtin_amdgcn_sinf(rev);
            }
            float ix = fmaf(p, 500.0f, 499.5f);        // [-0.5, 999.5]
            float xf = floorf(ix);
            float t  = ix - xf;
            // clamp (insurance; ix can't leave [-1,1000)) -> v_med3_f32
            float xfc = fminf(fmaxf(xf, -1.0f), 999.0f);
            int base  = (int)xfc;

            // Factored Keys weights.
            float u   = 1.0f - t;
            float tu  = t * u;
            float atu = A_C * tu;
            float w0  = atu * u;
            float w3  = atu * t;
            float w1  = fmaf(fmaf(A_C + 2.0f, t, -(A_C + 3.0f)), t * t, 1.0f);
            float w2  = 1.0f - w0 - w1 - w3;

            // 4 consecutive padded taps at padded index base+1 >= 0;
            // adjacent pairs -> compiler can fuse to ds_read2_b32.
            const __half2* tap = (s ? lrow1 : lrow0) + (base + 1);
            __half2 t0 = tap[0], t1 = tap[1], t2 = tap[2], t3 = tap[3];
            __half2 acc = __hmul2(t0, __float2half2_rn(w0));
            acc = __hfma2(t1, __float2half2_rn(w1), acc);
            acc = __hfma2(t2, __float2half2_rn(w2), acc);
            acc = __hfma2(t3, __float2half2_rn(w3), acc);
            o[s] = __half22float2(acc);
        }

        // float4 at b*8+np = (n0c0,n0c1,n1c0,n1c1); wave = 8b x 8np ->
        // 1KB contiguous full 128B lines, single writer, nontemporal.
        f32x4 v = { o[0].x, o[0].y, o[1].x, o[1].y };
        __builtin_nontemporal_store(v, op);

        xp += 65536 * 3;
        op += 65536 * 8;
    }
}

extern "C" void kernel_launch(void* const* d_in, const int* in_sizes, int n_in,
                              void* d_out, int out_size, void* d_ws, size_t ws_size,
                              hipStream_t stream) {
    const float* x     = (const float*)d_in[0];
    const float* grids = (const float*)d_in[1];
    const float* G     = (const float*)d_in[2];
    const float* H     = (const float*)d_in[3];
    float* out = (float*)d_out;
    trig_hashgrid<<<512, BLK, 0, stream>>>(x, grids, G, H, out);
}

// Round 10
// 167.293 us; speedup vs baseline: 1.1965x; 1.0354x over previous
//
#include <hip/hip_runtime.h>
#include <hip/hip_fp16.h>

// TrigHashGrid: B=1048576, IN_DIM=3, M=3, N=16, C=2, W=1000, A=-0.75
// R14: A/B on the nontemporal store flag (single diff vs R13).
// Evidence: 3 straight nulls on instruction diets => issue count not
// binding. R12: marginal 1.3-1.7us/iter ~ write demand (1.21), but
// aggregate write tput only ~3.3 TB/s vs 6.5 sustained by the (512MB,
// L3-overflowing) fill kernels => waves stall on store backpressure AND
// the path underperforms 2x. Theory: `nt` bypasses L2/L3 allocate and
// forces sectors to HBM in-window -- but our 128MB output FITS the 256MB
// Infinity Cache. Regular stores complete at cache speed, drain lazily.
// Everything else (16 levels/block, fp16 c-packed LDS, full-line
// single-writer float4 stores, prescaled G/H, strength-reduced pointers,
// unroll 4) unchanged from R13.

constexpr float A_C = -0.75f;

#define BLK 1024
#define WPAD 1004            // 2 + 1000 + 2 positions, one __half2 each

typedef float f32x4 __attribute__((ext_vector_type(4)));

__global__ __launch_bounds__(BLK, 8)
void trig_hashgrid(const float* __restrict__ x, const float* __restrict__ grids,
                   const float* __restrict__ G, const float* __restrict__ H,
                   float* __restrict__ out)
{
    __shared__ __half2 lds[16 * WPAD];        // 64256 B -> 2 blocks/CU
    const int tid = threadIdx.x;
    const int blk = blockIdx.x;               // 0..511

    // Zero the 4 pad positions per level row (padded w {0,1,1002,1003}).
    if (tid < 64) {
        int nl = tid >> 2, j = tid & 3;
        int off = (j < 2) ? j : (WPAD - 4 + j);
        lds[nl * WPAD + off] = __floats2half2_rn(0.0f, 0.0f);
    }
    // Stage all 16 levels as packed half2(c0,c1); 64 lanes/row, coalesced.
    {
        int row = tid >> 6;                   // 0..15
        int j   = tid & 63;
        const float* gsrc = grids + row * 2000;
        __half2* ldst = lds + row * WPAD;
        for (int w = j; w < 1000; w += 64)
            ldst[w + 2] = __floats2half2_rn(gsrc[w], gsrc[1000 + w]);
    }

    const int np = tid & 7;                   // level pair: n = 2np, 2np+1
    const int g  = tid >> 3;                  // 0..127
    const int n0 = 2 * np, n1 = n0 + 1;

    // Per-pair frequencies/phases, PRESCALED by 1/2pi (v_sin_f32 takes
    // revolutions): rev = x.G' + H' directly, no per-iter mul.
    constexpr float C2PI = 0.15915494309189535f;
    float Ga[2][3], Gb[2][3], Gc[2][3], Hh[2][3];
#pragma unroll
    for (int m = 0; m < 3; ++m) {
        Ga[0][m] = G[0*48 + m*16 + n0] * C2PI; Ga[1][m] = G[0*48 + m*16 + n1] * C2PI;
        Gb[0][m] = G[1*48 + m*16 + n0] * C2PI; Gb[1][m] = G[1*48 + m*16 + n1] * C2PI;
        Gc[0][m] = G[2*48 + m*16 + n0] * C2PI; Gc[1][m] = G[2*48 + m*16 + n1] * C2PI;
        Hh[0][m] = H[m*16 + n0] * C2PI;        Hh[1][m] = H[m*16 + n1] * C2PI;
    }
    __syncthreads();

    const __half2* lrow0 = &lds[n0 * WPAD];
    const __half2* lrow1 = &lds[n1 * WPAD];

    // Strength-reduced pointers: b = blk*128 + g + i*65536.
    const float* xp = x + (blk * 128 + g) * 3;          // += 65536*3 per iter
    f32x4*       op = (f32x4*)out + (blk * 128 + g) * 8 + np;  // += 65536*8

    // 16 iterations, b stride 65536; two independent chains per thread.
#pragma unroll 4
    for (int i = 0; i < 16; ++i) {
        float x0 = xp[0];
        float x1 = xp[1];
        float x2 = xp[2];

        float2 o[2];
#pragma unroll
        for (int s = 0; s < 2; ++s) {
            float p = 1.0f;
#pragma unroll
            for (int m = 0; m < 3; ++m) {
                float rev = fmaf(x0, Ga[s][m],
                            fmaf(x1, Gb[s][m],
                            fmaf(x2, Gc[s][m], Hh[s][m])));
                rev = __builtin_amdgcn_fractf(rev);
                p *= __builtin_amdgcn_sinf(rev);
            }
            float ix = fmaf(p, 500.0f, 499.5f);        // [-0.5, 999.5]
            float xf = floorf(ix);
            float t  = ix - xf;
            // clamp (insurance; ix can't leave [-1,1000)) -> v_med3_f32
            float xfc = fminf(fmaxf(xf, -1.0f), 999.0f);
            int base  = (int)xfc;

            // Factored Keys weights.
            float u   = 1.0f - t;
            float tu  = t * u;
            float atu = A_C * tu;
            float w0  = atu * u;
            float w3  = atu * t;
            float w1  = fmaf(fmaf(A_C + 2.0f, t, -(A_C + 3.0f)), t * t, 1.0f);
            float w2  = 1.0f - w0 - w1 - w3;

            // 4 consecutive padded taps at padded index base+1 >= 0;
            // adjacent pairs -> ds_read2_b32 fusion.
            const __half2* tap = (s ? lrow1 : lrow0) + (base + 1);
            __half2 t0 = tap[0], t1 = tap[1], t2 = tap[2], t3 = tap[3];
            __half2 acc = __hmul2(t0, __float2half2_rn(w0));
            acc = __hfma2(t1, __float2half2_rn(w1), acc);
            acc = __hfma2(t2, __float2half2_rn(w2), acc);
            acc = __hfma2(t3, __float2half2_rn(w3), acc);
            o[s] = __half22float2(acc);
        }

        // float4 at b*8+np = (n0c0,n0c1,n1c0,n1c1); wave = 8b x 8np ->
        // 1KB contiguous full 128B lines, single writer. PLAIN store:
        // 128MB output fits the 256MB L3 -- let it absorb and drain lazily
        // (nt forced the HBM path in-window; A/B says which wins).
        f32x4 v = { o[0].x, o[0].y, o[1].x, o[1].y };
        *op = v;

        xp += 65536 * 3;
        op += 65536 * 8;
    }
}

extern "C" void kernel_launch(void* const* d_in, const int* in_sizes, int n_in,
                              void* d_out, int out_size, void* d_ws, size_t ws_size,
                              hipStream_t stream) {
    const float* x     = (const float*)d_in[0];
    const float* grids = (const float*)d_in[1];
    const float* G     = (const float*)d_in[2];
    const float* H     = (const float*)d_in[3];
    float* out = (float*)d_out;
    trig_hashgrid<<<512, BLK, 0, stream>>>(x, grids, G, H, out);
}